// Round 1
// baseline (487.137 us; speedup 1.0000x reference)
//
#include <hip/hip_runtime.h>
#include <math.h>

// MinGRU: B=8, S=8192, D=256, H=256, fp32 in/out.
// Structure:
//   K1 gemm_zh : fused dual GEMM (z-pre, h-pre) + sigmoid epilogue
//                writes a = (1-z) -> ws, b = z*h_tilde -> d_out (scratch)
//   K2 phaseA  : per-chunk (P,Q) scan summaries
//   K3 phaseB  : scan over chunk summaries -> incoming h per chunk
//   K4 phaseC  : replay chunks, overwrite d_out in place with h_t

constexpr int B_ = 8;
constexpr int S_ = 8192;
constexpr int D_ = 256;
constexpr int H_ = 256;
constexpr int M_ = B_ * S_;        // 65536 rows
constexpr int CHUNKS = 128;        // chunks per sequence
constexpr int CLEN = S_ / CHUNKS;  // 64 steps per chunk

__global__ __launch_bounds__(256) void gemm_zh(
    const float* __restrict__ x,
    const float* __restrict__ whw, const float* __restrict__ whb,
    const float* __restrict__ wzw, const float* __restrict__ wzb,
    float* __restrict__ a_out, float* __restrict__ b_out)
{
  // LDS tiles stored transposed: [k][m] / [k][h] so the inner loop does
  // 16B-aligned ds_read_b128 with only broadcast / 2-way (free) bank aliasing.
  __shared__ float xs[64][64];
  __shared__ float wzs[64][64];
  __shared__ float whs[64][64];

  const int tid = threadIdx.x;
  const int m0 = blockIdx.x * 64;
  const int h0 = blockIdx.y * 64;
  const int tx = tid & 15;   // -> 4 h-columns
  const int ty = tid >> 4;   // -> 4 m-rows
  const int lk = tx * 4;     // loader k-offset

  float accz[4][4] = {{0.f}};
  float acch[4][4] = {{0.f}};

  for (int k0 = 0; k0 < D_; k0 += 64) {
#pragma unroll
    for (int i = 0; i < 4; i++) {
      const int r = ty + 16 * i;
      float4 xv = *(const float4*)(x   + (size_t)(m0 + r) * D_ + k0 + lk);
      float4 zv = *(const float4*)(wzw + (size_t)(h0 + r) * D_ + k0 + lk);
      float4 hv = *(const float4*)(whw + (size_t)(h0 + r) * D_ + k0 + lk);
      xs[lk + 0][r] = xv.x; xs[lk + 1][r] = xv.y; xs[lk + 2][r] = xv.z; xs[lk + 3][r] = xv.w;
      wzs[lk + 0][r] = zv.x; wzs[lk + 1][r] = zv.y; wzs[lk + 2][r] = zv.z; wzs[lk + 3][r] = zv.w;
      whs[lk + 0][r] = hv.x; whs[lk + 1][r] = hv.y; whs[lk + 2][r] = hv.z; whs[lk + 3][r] = hv.w;
    }
    __syncthreads();
#pragma unroll 8
    for (int k = 0; k < 64; k++) {
      float4 xf = *(const float4*)&xs[k][ty * 4];
      float4 zf = *(const float4*)&wzs[k][tx * 4];
      float4 hf = *(const float4*)&whs[k][tx * 4];
      float xr[4] = {xf.x, xf.y, xf.z, xf.w};
      float zr[4] = {zf.x, zf.y, zf.z, zf.w};
      float hr[4] = {hf.x, hf.y, hf.z, hf.w};
#pragma unroll
      for (int i = 0; i < 4; i++) {
#pragma unroll
        for (int j = 0; j < 4; j++) {
          accz[i][j] = fmaf(xr[i], zr[j], accz[i][j]);
          acch[i][j] = fmaf(xr[i], hr[j], acch[i][j]);
        }
      }
    }
    __syncthreads();
  }

  const int colb = h0 + tx * 4;
  float zb[4], hb[4];
#pragma unroll
  for (int j = 0; j < 4; j++) { zb[j] = wzb[colb + j]; hb[j] = whb[colb + j]; }

#pragma unroll
  for (int i = 0; i < 4; i++) {
    const size_t row = (size_t)(m0 + ty * 4 + i);
    float4 av, bv;
    float* ap = (float*)&av;
    float* bp = (float*)&bv;
#pragma unroll
    for (int j = 0; j < 4; j++) {
      const float zpre = accz[i][j] + zb[j];
      const float hpre = acch[i][j] + hb[j];
      const float z = 1.0f / (1.0f + expf(-zpre));
      ap[j] = 1.0f - z;      // a_t
      bp[j] = z * hpre;      // b_t
    }
    *(float4*)(a_out + row * H_ + colb) = av;
    *(float4*)(b_out + row * H_ + colb) = bv;
  }
}

// Phase A: chunk summaries. h_out = P * h_in + Q over the chunk.
__global__ __launch_bounds__(256) void scan_phaseA(
    const float* __restrict__ a_arr, const float* __restrict__ b_arr,
    float* __restrict__ P_out, float* __restrict__ Q_out)
{
  const int c = blockIdx.x;
  const int b = blockIdx.y;
  const int h = threadIdx.x;
  size_t base = ((size_t)b * S_ + (size_t)c * CLEN) * H_ + h;
  float P = 1.0f, Q = 0.0f;
#pragma unroll 8
  for (int t = 0; t < CLEN; t++) {
    const float av = a_arr[base + (size_t)t * H_];
    const float bv = b_arr[base + (size_t)t * H_];
    Q = fmaf(av, Q, bv);
    P *= av;
  }
  const size_t idx = ((size_t)b * CHUNKS + c) * H_ + h;
  P_out[idx] = P;
  Q_out[idx] = Q;
}

// Phase B: sequential scan over chunk summaries -> incoming state per chunk.
__global__ __launch_bounds__(256) void scan_phaseB(
    const float* __restrict__ h0in, const float* __restrict__ P,
    const float* __restrict__ Q, float* __restrict__ hstate)
{
  const int b = blockIdx.x;
  const int h = threadIdx.x;
  float hc = h0in[(size_t)b * H_ + h];
  for (int c = 0; c < CHUNKS; c++) {
    const size_t idx = ((size_t)b * CHUNKS + c) * H_ + h;
    hstate[idx] = hc;
    hc = fmaf(P[idx], hc, Q[idx]);
  }
}

// Phase C: replay each chunk with its incoming state; b_arr aliases out
// (in-place overwrite). Loads batched 8-deep to keep them in flight.
__global__ __launch_bounds__(256) void scan_phaseC(
    const float* __restrict__ a_arr, const float* __restrict__ hstate,
    float* out)
{
  const int c = blockIdx.x;
  const int b = blockIdx.y;
  const int h = threadIdx.x;
  size_t base = ((size_t)b * S_ + (size_t)c * CLEN) * H_ + h;
  float hc = hstate[((size_t)b * CHUNKS + c) * H_ + h];
  for (int t0 = 0; t0 < CLEN; t0 += 8) {
    float av[8], bv[8];
#pragma unroll
    for (int j = 0; j < 8; j++) {
      av[j] = a_arr[base + (size_t)(t0 + j) * H_];
      bv[j] = out[base + (size_t)(t0 + j) * H_];
    }
#pragma unroll
    for (int j = 0; j < 8; j++) {
      hc = fmaf(av[j], hc, bv[j]);
      out[base + (size_t)(t0 + j) * H_] = hc;
    }
  }
}

extern "C" void kernel_launch(void* const* d_in, const int* in_sizes, int n_in,
                              void* d_out, int out_size, void* d_ws, size_t ws_size,
                              hipStream_t stream) {
  const float* x   = (const float*)d_in[0];
  const float* h0  = (const float*)d_in[1];
  const float* whw = (const float*)d_in[2];
  const float* whb = (const float*)d_in[3];
  const float* wzw = (const float*)d_in[4];
  const float* wzb = (const float*)d_in[5];
  float* out = (float*)d_out;

  float* a_arr  = (float*)d_ws;                      // [M, H]  (1 - z)
  float* chunkP = a_arr  + (size_t)M_ * H_;          // [B, CHUNKS, H]
  float* chunkQ = chunkP + (size_t)B_ * CHUNKS * H_; // [B, CHUNKS, H]
  float* hstate = chunkQ + (size_t)B_ * CHUNKS * H_; // [B, CHUNKS, H]
  // b_t = z * h_tilde lives in d_out (overwritten in place by phase C).

  dim3 gGemm(M_ / 64, H_ / 64);
  gemm_zh<<<gGemm, 256, 0, stream>>>(x, whw, whb, wzw, wzb, a_arr, out);

  dim3 gScan(CHUNKS, B_);
  scan_phaseA<<<gScan, 256, 0, stream>>>(a_arr, out, chunkP, chunkQ);
  scan_phaseB<<<B_, 256, 0, stream>>>(h0, chunkP, chunkQ, hstate);
  scan_phaseC<<<gScan, 256, 0, stream>>>(a_arr, hstate, out);
}

// Round 2
// 197.834 us; speedup vs baseline: 2.4623x; 2.4623x over previous
//
#include <hip/hip_runtime.h>
#include <math.h>

// MinGRU: B=8, S=8192, D=256, H=256, fp32 in/out.
//   K1 gemm_zh : bf16-MFMA dual GEMM (z-pre, h-pre) + fused sigmoid epilogue,
//                writes packed {a=1-z (lo16), b=z*h_tilde (hi16)} bf16 -> ws
//   K2 phaseA  : per-chunk (P,Q) scan summaries (fp32)
//   K3 phaseB  : sequential scan over chunk summaries -> incoming h per chunk
//   K4 phaseC  : replay chunks, write fp32 h_t -> d_out

constexpr int B_ = 8;
constexpr int S_ = 8192;
constexpr int D_ = 256;
constexpr int H_ = 256;
constexpr int M_ = B_ * S_;        // 65536 rows
constexpr int CHUNKS = 128;
constexpr int CLEN = S_ / CHUNKS;  // 64

typedef __attribute__((ext_vector_type(8))) short bf16x8;
typedef __attribute__((ext_vector_type(4))) float f32x4;

__device__ __forceinline__ ushort f2bf(float f) {
  union { float f; uint u; } v; v.f = f;
  const uint r = v.u + 0x7FFFu + ((v.u >> 16) & 1u);  // RNE
  return (ushort)(r >> 16);
}

// ---------------------------------------------------------------- GEMM ----
// Block: 256 thr = 4 waves. Tile: 128 rows x 64 h-channels, both projections.
// LDS tiles padded to 72 bf16/row: fragment ds_read_b128 lands 8 lanes per
// 4-bank group with distinct rows = minimum cycles (no excess conflicts).
__global__ __launch_bounds__(256) void gemm_zh(
    const float* __restrict__ x,
    const float* __restrict__ whw, const float* __restrict__ whb,
    const float* __restrict__ wzw, const float* __restrict__ wzb,
    uint* __restrict__ ab)
{
  __shared__ ushort xs[128][72];
  __shared__ ushort wzs[64][72];
  __shared__ ushort whs[64][72];

  const int tid = threadIdx.x;
  // XCD swizzle: each 128-row x-panel consumed by exactly one XCD (g%8),
  // its 4 n-tiles consecutive in that XCD's local order -> x fetched once.
  const int g    = blockIdx.x;
  const int xcd  = g & 7;
  const int loc  = g >> 3;
  const int nt   = loc & 3;
  const int panel = (loc >> 2) * 8 + xcd;
  const int m0 = panel * 128;
  const int n0 = nt * 64;

  const int lane = tid & 63;
  const int w  = tid >> 6;
  const int mb = (w & 1) * 64;   // wave row quadrant
  const int nb = (w >> 1) * 32;  // wave col half (within 64 channels)
  const int q  = lane >> 4;
  const int cn = lane & 15;

  f32x4 accz[4][2] = {};
  f32x4 acch[4][2] = {};

  for (int k0 = 0; k0 < D_; k0 += 64) {
    __syncthreads();  // WAR guard on LDS reuse
#pragma unroll
    for (int f = 0; f < 8; f++) {  // x tile: 128 rows x 64 k (fp32 -> bf16)
      const int idx = tid + 256 * f;
      const int row = idx >> 4, seg = idx & 15;
      float4 v = *(const float4*)(x + (size_t)(m0 + row) * D_ + k0 + seg * 4);
      *(ushort4*)&xs[row][seg * 4] =
          make_ushort4(f2bf(v.x), f2bf(v.y), f2bf(v.z), f2bf(v.w));
    }
#pragma unroll
    for (int f = 0; f < 4; f++) {  // weight tiles: 64 rows x 64 k each
      const int idx = tid + 256 * f;
      const int row = idx >> 4, seg = idx & 15;
      float4 vz = *(const float4*)(wzw + (size_t)(n0 + row) * D_ + k0 + seg * 4);
      float4 vh = *(const float4*)(whw + (size_t)(n0 + row) * D_ + k0 + seg * 4);
      *(ushort4*)&wzs[row][seg * 4] =
          make_ushort4(f2bf(vz.x), f2bf(vz.y), f2bf(vz.z), f2bf(vz.w));
      *(ushort4*)&whs[row][seg * 4] =
          make_ushort4(f2bf(vh.x), f2bf(vh.y), f2bf(vh.z), f2bf(vh.w));
    }
    __syncthreads();
#pragma unroll
    for (int ks = 0; ks < 2; ks++) {
      const int kk = ks * 32 + q * 8;  // A[m=lane&15][k=quad*8+j]
      bf16x8 af[4], bz[2], bh[2];
#pragma unroll
      for (int i = 0; i < 4; i++)
        af[i] = *(const bf16x8*)&xs[mb + i * 16 + cn][kk];
#pragma unroll
      for (int j = 0; j < 2; j++) {
        bz[j] = *(const bf16x8*)&wzs[nb + j * 16 + cn][kk];
        bh[j] = *(const bf16x8*)&whs[nb + j * 16 + cn][kk];
      }
#pragma unroll
      for (int i = 0; i < 4; i++)
#pragma unroll
        for (int j = 0; j < 2; j++) {
          accz[i][j] = __builtin_amdgcn_mfma_f32_16x16x32_bf16(af[i], bz[j], accz[i][j], 0, 0, 0);
          acch[i][j] = __builtin_amdgcn_mfma_f32_16x16x32_bf16(af[i], bh[j], acch[i][j], 0, 0, 0);
        }
    }
  }

  // Epilogue: C/D layout col=lane&15, row=quad*4+reg. Pack a,b -> uint32.
#pragma unroll
  for (int j = 0; j < 2; j++) {
    const int ch = n0 + nb + j * 16 + cn;
    const float zb = wzb[ch], hb = whb[ch];
#pragma unroll
    for (int i = 0; i < 4; i++) {
#pragma unroll
      for (int r = 0; r < 4; r++) {
        const int row = m0 + mb + i * 16 + q * 4 + r;
        const float zpre = accz[i][j][r] + zb;
        const float hpre = acch[i][j][r] + hb;
        const float zs = 1.0f / (1.0f + __expf(-zpre));
        const ushort ua = f2bf(1.0f - zs);
        const ushort ub = f2bf(zs * hpre);
        ab[(size_t)row * H_ + ch] = ((uint)ub << 16) | (uint)ua;
      }
    }
  }
}

// ---------------------------------------------------------------- scans ---
// Phase A: chunk summaries h_out = P*h_in + Q. 2 channels/thread, 2 waves
// per chunk -> 2048 waves (8/CU); 8-deep load batching hides HBM latency.
__global__ __launch_bounds__(256) void scan_phaseA(
    const uint* __restrict__ ab,
    float* __restrict__ P_out, float* __restrict__ Q_out)
{
  const int half = threadIdx.x >> 7;
  const int lt   = threadIdx.x & 127;
  const int c = blockIdx.x * 2 + half;
  const int b = blockIdx.y;
  const int ch = lt * 2;
  size_t base = ((size_t)b * S_ + (size_t)c * CLEN) * H_ + ch;
  float P0 = 1.f, P1 = 1.f, Q0 = 0.f, Q1 = 0.f;
  for (int t0 = 0; t0 < CLEN; t0 += 8) {
    uint2 v[8];
#pragma unroll
    for (int j = 0; j < 8; j++)
      v[j] = *(const uint2*)(ab + base + (size_t)(t0 + j) * H_);
#pragma unroll
    for (int j = 0; j < 8; j++) {
      const float a0 = __uint_as_float(v[j].x << 16);
      const float b0 = __uint_as_float(v[j].x & 0xFFFF0000u);
      const float a1 = __uint_as_float(v[j].y << 16);
      const float b1 = __uint_as_float(v[j].y & 0xFFFF0000u);
      Q0 = fmaf(a0, Q0, b0); P0 *= a0;
      Q1 = fmaf(a1, Q1, b1); P1 *= a1;
    }
  }
  const size_t idx = ((size_t)b * CHUNKS + c) * H_ + ch;
  *(float2*)(P_out + idx) = make_float2(P0, P1);
  *(float2*)(Q_out + idx) = make_float2(Q0, Q1);
}

// Phase B: sequential scan over chunk summaries.
__global__ __launch_bounds__(256) void scan_phaseB(
    const float* __restrict__ h0in, const float* __restrict__ P,
    const float* __restrict__ Q, float* __restrict__ hstate)
{
  const int b = blockIdx.x;
  const int h = threadIdx.x;
  float hc = h0in[(size_t)b * H_ + h];
  for (int c = 0; c < CHUNKS; c++) {
    const size_t idx = ((size_t)b * CHUNKS + c) * H_ + h;
    hstate[idx] = hc;
    hc = fmaf(P[idx], hc, Q[idx]);
  }
}

// Phase C: replay each chunk from its incoming state, write fp32 out.
__global__ __launch_bounds__(256) void scan_phaseC(
    const uint* __restrict__ ab, const float* __restrict__ hstate,
    float* __restrict__ out)
{
  const int half = threadIdx.x >> 7;
  const int lt   = threadIdx.x & 127;
  const int c = blockIdx.x * 2 + half;
  const int b = blockIdx.y;
  const int ch = lt * 2;
  size_t base = ((size_t)b * S_ + (size_t)c * CLEN) * H_ + ch;
  float2 h = *(const float2*)(hstate + ((size_t)b * CHUNKS + c) * H_ + ch);
  for (int t0 = 0; t0 < CLEN; t0 += 8) {
    uint2 v[8];
#pragma unroll
    for (int j = 0; j < 8; j++)
      v[j] = *(const uint2*)(ab + base + (size_t)(t0 + j) * H_);
#pragma unroll
    for (int j = 0; j < 8; j++) {
      const float a0 = __uint_as_float(v[j].x << 16);
      const float b0 = __uint_as_float(v[j].x & 0xFFFF0000u);
      const float a1 = __uint_as_float(v[j].y << 16);
      const float b1 = __uint_as_float(v[j].y & 0xFFFF0000u);
      h.x = fmaf(a0, h.x, b0);
      h.y = fmaf(a1, h.y, b1);
      *(float2*)(out + base + (size_t)(t0 + j) * H_) = h;
    }
  }
}

extern "C" void kernel_launch(void* const* d_in, const int* in_sizes, int n_in,
                              void* d_out, int out_size, void* d_ws, size_t ws_size,
                              hipStream_t stream) {
  const float* x   = (const float*)d_in[0];
  const float* h0  = (const float*)d_in[1];
  const float* whw = (const float*)d_in[2];
  const float* whb = (const float*)d_in[3];
  const float* wzw = (const float*)d_in[4];
  const float* wzb = (const float*)d_in[5];
  float* out = (float*)d_out;

  uint*  ab     = (uint*)d_ws;                        // [M,H] packed bf16 {a,b}
  float* chunkP = (float*)(ab + (size_t)M_ * H_);     // [B,CHUNKS,H]
  float* chunkQ = chunkP + (size_t)B_ * CHUNKS * H_;  // [B,CHUNKS,H]
  float* hstate = chunkQ + (size_t)B_ * CHUNKS * H_;  // [B,CHUNKS,H]

  gemm_zh<<<(M_ / 128) * 4, 256, 0, stream>>>(x, whw, whb, wzw, wzb, ab);
  scan_phaseA<<<dim3(CHUNKS / 2, B_), 256, 0, stream>>>(ab, chunkP, chunkQ);
  scan_phaseB<<<B_, 256, 0, stream>>>(h0, chunkP, chunkQ, hstate);
  scan_phaseC<<<dim3(CHUNKS / 2, B_), 256, 0, stream>>>(ab, hstate, out);
}

// Round 3
// 196.751 us; speedup vs baseline: 2.4759x; 1.0055x over previous
//
#include <hip/hip_runtime.h>
#include <math.h>

// MinGRU: B=8, S=8192, D=256, H=256, fp32 in/out.
//   K1 gemm_zh : bf16-MFMA dual GEMM (z,h) + sigmoid epilogue + FUSED phase-A
//                (per-chunk P,Q summaries via LDS round-trip).
//                Conversions use u+=0x8000 then v_perm_b32 (2 floats/op).
//   K2 phaseB  : sequential scan over chunk summaries (batched loads)
//   K3 phaseC  : replay chunks, 4 ch/thread uint4 loads, fp32 out

constexpr int B_ = 8;
constexpr int S_ = 8192;
constexpr int D_ = 256;
constexpr int H_ = 256;
constexpr int M_ = B_ * S_;        // 65536 rows
constexpr int CHUNKS = 128;
constexpr int CLEN = S_ / CHUNKS;  // 64

typedef __attribute__((ext_vector_type(8))) short bf16x8;
typedef __attribute__((ext_vector_type(4))) float f32x4;

// Pack 2 floats -> 2 bf16 (round-to-nearest, ties-away) in one v_perm_b32.
// Result: bf16(f1) in hi16, bf16(f0) in lo16.
__device__ __forceinline__ uint pack2bf(float f0, float f1) {
  const uint u0 = __float_as_uint(f0) + 0x8000u;
  const uint u1 = __float_as_uint(f1) + 0x8000u;
  return __builtin_amdgcn_perm(u1, u0, 0x07060302u);
}

// ---------------------------------------------------------------- GEMM ----
union SMem {
  struct {
    ushort xs[128][72];   // x tile, +8 pad: conflict-free b128 frag reads
    ushort wzs[64][72];
    ushort whs[64][72];
  } s;
  uint abt[128][66];      // epilogue a,b tile for fused phase-A (+2 pad)
};

__global__ __launch_bounds__(256) void gemm_zh(
    const float* __restrict__ x,
    const float* __restrict__ whw, const float* __restrict__ whb,
    const float* __restrict__ wzw, const float* __restrict__ wzb,
    uint* __restrict__ ab,
    float* __restrict__ P_out, float* __restrict__ Q_out)
{
  __shared__ SMem sm;

  const int tid = threadIdx.x;
  // XCD swizzle: one 128-row x-panel per XCD group -> x fetched ~once.
  const int g    = blockIdx.x;
  const int xcd  = g & 7;
  const int loc  = g >> 3;
  const int nt   = loc & 3;
  const int panel = (loc >> 2) * 8 + xcd;
  const int m0 = panel * 128;
  const int n0 = nt * 64;

  const int lane = tid & 63;
  const int w  = tid >> 6;
  const int mb = (w & 1) * 64;
  const int nb = (w >> 1) * 32;
  const int q  = lane >> 4;
  const int cn = lane & 15;

  f32x4 accz[4][2] = {};
  f32x4 acch[4][2] = {};

  for (int k0 = 0; k0 < D_; k0 += 64) {
    __syncthreads();
#pragma unroll
    for (int f = 0; f < 8; f++) {  // x: 128 rows x 64 k
      const int idx = tid + 256 * f;
      const int row = idx >> 4, seg = idx & 15;
      float4 v = *(const float4*)(x + (size_t)(m0 + row) * D_ + k0 + seg * 4);
      *(uint2*)&sm.s.xs[row][seg * 4] =
          make_uint2(pack2bf(v.x, v.y), pack2bf(v.z, v.w));
    }
#pragma unroll
    for (int f = 0; f < 4; f++) {  // weights: 64 rows x 64 k each
      const int idx = tid + 256 * f;
      const int row = idx >> 4, seg = idx & 15;
      float4 vz = *(const float4*)(wzw + (size_t)(n0 + row) * D_ + k0 + seg * 4);
      float4 vh = *(const float4*)(whw + (size_t)(n0 + row) * D_ + k0 + seg * 4);
      *(uint2*)&sm.s.wzs[row][seg * 4] =
          make_uint2(pack2bf(vz.x, vz.y), pack2bf(vz.z, vz.w));
      *(uint2*)&sm.s.whs[row][seg * 4] =
          make_uint2(pack2bf(vh.x, vh.y), pack2bf(vh.z, vh.w));
    }
    __syncthreads();
#pragma unroll
    for (int ks = 0; ks < 2; ks++) {
      const int kk = ks * 32 + q * 8;  // A[m=lane&15][k=quad*8+j]
      bf16x8 af[4], bz[2], bh[2];
#pragma unroll
      for (int i = 0; i < 4; i++)
        af[i] = *(const bf16x8*)&sm.s.xs[mb + i * 16 + cn][kk];
#pragma unroll
      for (int j = 0; j < 2; j++) {
        bz[j] = *(const bf16x8*)&sm.s.wzs[nb + j * 16 + cn][kk];
        bh[j] = *(const bf16x8*)&sm.s.whs[nb + j * 16 + cn][kk];
      }
#pragma unroll
      for (int i = 0; i < 4; i++)
#pragma unroll
        for (int j = 0; j < 2; j++) {
          accz[i][j] = __builtin_amdgcn_mfma_f32_16x16x32_bf16(af[i], bz[j], accz[i][j], 0, 0, 0);
          acch[i][j] = __builtin_amdgcn_mfma_f32_16x16x32_bf16(af[i], bh[j], acch[i][j], 0, 0, 0);
        }
    }
  }

  __syncthreads();  // staging LDS dead; safe to alias as abt

  // Epilogue: C/D col=lane&15, row=quad*4+reg. Pack {b(hi),a(lo)} bf16.
#pragma unroll
  for (int j = 0; j < 2; j++) {
    const int chl = nb + j * 16 + cn;
    const int ch = n0 + chl;
    const float zb = wzb[ch], hb = whb[ch];
#pragma unroll
    for (int i = 0; i < 4; i++) {
#pragma unroll
      for (int r = 0; r < 4; r++) {
        const int rowl = mb + i * 16 + q * 4 + r;
        const float zpre = accz[i][j][r] + zb;
        const float hpre = acch[i][j][r] + hb;
        const float zs = 1.0f / (1.0f + __expf(-zpre));
        const uint packed = pack2bf(1.0f - zs, zs * hpre);
        ab[(size_t)(m0 + rowl) * H_ + ch] = packed;
        sm.abt[rowl][chl] = packed;
      }
    }
  }

  __syncthreads();

  // Fused phase-A: 128 threads -> (chunk 0/1) x (64 channels).
  if (tid < 128) {
    const int k = tid >> 6;        // local chunk
    const int chl = tid & 63;
    float P = 1.0f, Q = 0.0f;
#pragma unroll 8
    for (int t = 0; t < CLEN; t++) {
      const uint v = sm.abt[k * 64 + t][chl];
      const float a = __uint_as_float(v << 16);
      const float b = __uint_as_float(v & 0xFFFF0000u);
      Q = fmaf(a, Q, b);
      P *= a;
    }
    const int bidx = m0 / S_;
    const int cglob = (m0 % S_) / CLEN + k;
    const size_t idx = ((size_t)bidx * CHUNKS + cglob) * H_ + n0 + chl;
    P_out[idx] = P;
    Q_out[idx] = Q;
  }
}

// ---------------------------------------------------------------- scans ---
// Phase B: sequential scan over chunk summaries, 8-deep batched loads.
__global__ __launch_bounds__(256) void scan_phaseB(
    const float* __restrict__ h0in, const float* __restrict__ P,
    const float* __restrict__ Q, float* __restrict__ hstate)
{
  const int b = blockIdx.x;
  const int h = threadIdx.x;
  const size_t base = (size_t)b * CHUNKS * H_ + h;
  float hc = h0in[(size_t)b * H_ + h];
  for (int c0 = 0; c0 < CHUNKS; c0 += 8) {
    float p[8], q[8];
#pragma unroll
    for (int j = 0; j < 8; j++) {
      p[j] = P[base + (size_t)(c0 + j) * H_];
      q[j] = Q[base + (size_t)(c0 + j) * H_];
    }
#pragma unroll
    for (int j = 0; j < 8; j++) {
      hstate[base + (size_t)(c0 + j) * H_] = hc;
      hc = fmaf(p[j], hc, q[j]);
    }
  }
}

// Phase C: replay. 1 wave per (b,chunk): 64 lanes x 4 channels, uint4 loads.
__global__ __launch_bounds__(256) void scan_phaseC(
    const uint* __restrict__ ab, const float* __restrict__ hstate,
    float* __restrict__ out)
{
  const int pair = blockIdx.x * 4 + (threadIdx.x >> 6);
  const int b = pair >> 7;
  const int c = pair & 127;
  const int ch = (threadIdx.x & 63) * 4;
  const size_t base = ((size_t)b * S_ + (size_t)c * CLEN) * H_ + ch;
  float4 h = *(const float4*)(hstate + ((size_t)b * CHUNKS + c) * H_ + ch);
  for (int t0 = 0; t0 < CLEN; t0 += 8) {
    uint4 v[8];
#pragma unroll
    for (int j = 0; j < 8; j++)
      v[j] = *(const uint4*)(ab + base + (size_t)(t0 + j) * H_);
#pragma unroll
    for (int j = 0; j < 8; j++) {
      h.x = fmaf(__uint_as_float(v[j].x << 16), h.x, __uint_as_float(v[j].x & 0xFFFF0000u));
      h.y = fmaf(__uint_as_float(v[j].y << 16), h.y, __uint_as_float(v[j].y & 0xFFFF0000u));
      h.z = fmaf(__uint_as_float(v[j].z << 16), h.z, __uint_as_float(v[j].z & 0xFFFF0000u));
      h.w = fmaf(__uint_as_float(v[j].w << 16), h.w, __uint_as_float(v[j].w & 0xFFFF0000u));
      *(float4*)(out + base + (size_t)(t0 + j) * H_) = h;
    }
  }
}

extern "C" void kernel_launch(void* const* d_in, const int* in_sizes, int n_in,
                              void* d_out, int out_size, void* d_ws, size_t ws_size,
                              hipStream_t stream) {
  const float* x   = (const float*)d_in[0];
  const float* h0  = (const float*)d_in[1];
  const float* whw = (const float*)d_in[2];
  const float* whb = (const float*)d_in[3];
  const float* wzw = (const float*)d_in[4];
  const float* wzb = (const float*)d_in[5];
  float* out = (float*)d_out;

  uint*  ab     = (uint*)d_ws;                        // [M,H] packed bf16 {b,a}
  float* chunkP = (float*)(ab + (size_t)M_ * H_);     // [B,CHUNKS,H]
  float* chunkQ = chunkP + (size_t)B_ * CHUNKS * H_;  // [B,CHUNKS,H]
  float* hstate = chunkQ + (size_t)B_ * CHUNKS * H_;  // [B,CHUNKS,H]

  gemm_zh<<<(M_ / 128) * 4, 256, 0, stream>>>(x, whw, whb, wzw, wzb,
                                              ab, chunkP, chunkQ);
  scan_phaseB<<<B_, 256, 0, stream>>>(h0, chunkP, chunkQ, hstate);
  scan_phaseC<<<(B_ * CHUNKS) / 4, 256, 0, stream>>>(ab, hstate, out);
}